// Round 5
// baseline (218.953 us; speedup 1.0000x reference)
//
#include <hip/hip_runtime.h>
#include <hip/hip_bf16.h>

typedef __attribute__((ext_vector_type(8))) short bf16x8;
typedef __attribute__((ext_vector_type(4))) float f32x4;

#define MFMA16(a, b, c) __builtin_amdgcn_mfma_f32_16x16x32_bf16((a), (b), (c), 0, 0, 0)
#define ASYNC16(g, l)                                                     \
    __builtin_amdgcn_global_load_lds(                                     \
        (const __attribute__((address_space(1))) void*)(g),               \
        (__attribute__((address_space(3))) void*)(l), 16, 0, 0)

constexpr int B_ = 2, S_ = 2048, E_ = 1024, NH_ = 16, NKV_ = 4, HD_ = 64;

// ---------------------------------------------------------------------------
// fp32 -> bf16 conversion, flat 1D grid. (unchanged, r4-verified)
// ---------------------------------------------------------------------------
__global__ __launch_bounds__(256) void cvt_all(
    const float* __restrict__ s0, const float* __restrict__ s1,
    const float* __restrict__ s2, const float* __restrict__ s3,
    const float* __restrict__ s4, const float* __restrict__ s5,
    const float* __restrict__ s6,
    __hip_bfloat16* __restrict__ d0, __hip_bfloat16* __restrict__ d1,
    __hip_bfloat16* __restrict__ d2, __hip_bfloat16* __restrict__ d3,
    __hip_bfloat16* __restrict__ d4, __hip_bfloat16* __restrict__ d5,
    __hip_bfloat16* __restrict__ d6)
{
    int id = blockIdx.x;
    const float* s;
    __hip_bfloat16* d;
    if (id < 6144) {
        const int which = id >> 11;
        s = which == 0 ? s0 : (which == 1 ? s1 : s2);
        d = which == 0 ? d0 : (which == 1 ? d1 : d2);
        id &= 2047;
    } else if (id < 6656) { s = s3; d = d3; id -= 6144; }
    else if (id < 7168)   { s = s4; d = d4; id -= 6656; }
    else if (id < 7296)   { s = s5; d = d5; id -= 7168; }
    else                  { s = s6; d = d6; id -= 7296; }

    const size_t i = ((size_t)id * 256 + threadIdx.x) * 8;
    const float4 f0 = *reinterpret_cast<const float4*>(s + i);
    const float4 f1 = *reinterpret_cast<const float4*>(s + i + 4);
    union { __hip_bfloat16 h[8]; uint4 u; } t;
    t.h[0] = __float2bfloat16(f0.x); t.h[1] = __float2bfloat16(f0.y);
    t.h[2] = __float2bfloat16(f0.z); t.h[3] = __float2bfloat16(f0.w);
    t.h[4] = __float2bfloat16(f1.x); t.h[5] = __float2bfloat16(f1.y);
    t.h[6] = __float2bfloat16(f1.z); t.h[7] = __float2bfloat16(f1.w);
    *reinterpret_cast<uint4*>(d + i) = t.u;
}

// ---------------------------------------------------------------------------
// bf16 B^T GEMM core r5: same 64x128 tile / staging / fragment geometry as
// r4 (verified), but the 2-buffer barrier-drain loop is replaced by a
// 3-buffer depth-2 COUNTED-VMCNT pipeline (T4, m218 pattern):
//   [sched_barrier; vmcnt(6); s_barrier; STAGE(t+2); compute(t)]
// vmcnt never drains to 0 in the main loop -> loads stay in flight across
// barriers; last iteration peeled with vmcnt(0).
// Race audit: barrier at iter t follows compute(t-1) for every wave, so
// STAGE(t+2) overwriting buffer (t+2)%3 == (t-1)%3 is safe; per-wave
// vmcnt(6) before the barrier ensures ALL waves' tile-t loads landed.
// LDS: 3 x (4096 + 8192) elems = 72 KB -> 2 blocks/CU.
// ---------------------------------------------------------------------------
__device__ __forceinline__ void gemm_core(
    const __hip_bfloat16* __restrict__ A,
    const __hip_bfloat16* __restrict__ W,
    void* __restrict__ C,
    const int N, const int mode, const int m0, const int n0,
    __hip_bfloat16* sA, __hip_bfloat16* sW)
{
    const int tid  = threadIdx.x;
    const int l    = tid & 63;
    const int w    = tid >> 6;
    const int quad = l >> 4;
    const int lan  = l & 15;
    const int wm   = (w >> 1) * 32;
    const int wn   = (w & 1) * 64;

    // staging: per 32-row block wave w covers rows w*8..w*8+7; lane writes
    // LDS bytes base + l*16 (gload_lds contract: wave-uniform base + l*16).
    const int srow  = w * 8 + (l >> 3);
    const int scolL = (l & 7) * 8;                // linear LDS col (elems)
    const int scolG = ((l & 7) ^ (l >> 3)) * 8;   // inverse-swz global col

    f32x4 acc[2][4] = {};

    // 6 gload_lds per thread per STAGE (2 A + 4 W).
#define STAGE(buf, kb)                                                    \
    {                                                                     \
        _Pragma("unroll")                                                 \
        for (int q = 0; q < 2; ++q) {                                     \
            const int r_ = q * 32 + srow;                                 \
            ASYNC16(A + (size_t)(m0 + r_) * E_ + (kb) + scolG,            \
                    sA + (buf) * 4096 + r_ * 64 + scolL);                 \
        }                                                                 \
        _Pragma("unroll")                                                 \
        for (int q = 0; q < 4; ++q) {                                     \
            const int r_ = q * 32 + srow;                                 \
            ASYNC16(W + (size_t)(n0 + r_) * E_ + (kb) + scolG,            \
                    sW + (buf) * 8192 + r_ * 64 + scolL);                 \
        }                                                                 \
    }

#define COMPUTE(buf)                                                      \
    {                                                                     \
        _Pragma("unroll")                                                 \
        for (int kk = 0; kk < 2; ++kk) {                                  \
            bf16x8 af[2], bf[4];                                          \
            const int ca = ((kk * 4 + quad) ^ (lan & 7)) * 8;             \
            _Pragma("unroll")                                             \
            for (int i = 0; i < 2; ++i)                                   \
                af[i] = *reinterpret_cast<const bf16x8*>(                 \
                    sA + (buf) * 4096 + (wm + i * 16 + lan) * 64 + ca);   \
            _Pragma("unroll")                                             \
            for (int j = 0; j < 4; ++j)                                   \
                bf[j] = *reinterpret_cast<const bf16x8*>(                 \
                    sW + (buf) * 8192 + (wn + j * 16 + lan) * 64 + ca);   \
            _Pragma("unroll")                                             \
            for (int i = 0; i < 2; ++i)                                   \
                _Pragma("unroll")                                         \
                for (int j = 0; j < 4; ++j)                               \
                    acc[i][j] = MFMA16(af[i], bf[j], acc[i][j]);          \
        }                                                                 \
    }

    STAGE(0, 0)
    STAGE(1, 64)
    int cur = 0;
#pragma unroll 1
    for (int t = 0; t < 15; ++t) {
        __builtin_amdgcn_sched_barrier(0);          // pin prior ds_reads
        asm volatile("s_waitcnt vmcnt(6)" ::: "memory");  // tile t landed
        __builtin_amdgcn_s_barrier();
        if (t < 14) {
            int nb = cur + 2; if (nb >= 3) nb -= 3;
            STAGE(nb, (t + 2) * 64)
        }
        COMPUTE(cur)
        cur = (cur == 2) ? 0 : cur + 1;
    }
    __builtin_amdgcn_sched_barrier(0);
    asm volatile("s_waitcnt vmcnt(0)" ::: "memory");    // tile 15 landed
    __builtin_amdgcn_s_barrier();
    COMPUTE(cur)
#undef STAGE
#undef COMPUTE

#pragma unroll
    for (int i = 0; i < 2; ++i)
#pragma unroll
        for (int j = 0; j < 4; ++j)
#pragma unroll
            for (int r = 0; r < 4; ++r) {
                const int gm = m0 + wm + i * 16 + quad * 4 + r;
                const int gn = n0 + wn + j * 16 + lan;
                const float v = acc[i][j][r];
                if (mode == 2) {
                    ((float*)C)[(size_t)gm * N + gn] = v;
                } else {
                    const __hip_bfloat16 hv = __float2bfloat16(v);
                    if (mode == 0)
                        ((__hip_bfloat16*)C)[(size_t)gm * N + gn] = hv;
                    else  // V-transpose: [B,NKV,HD,S]
                        ((__hip_bfloat16*)C)
                            [((size_t)(gm >> 11) * N + gn) * (size_t)S_ +
                             (gm & 2047)] = hv;
                }
            }
}

// Fused Q/K/V projections, 64x128 tiles: blocks [0,512) = Q, [512,640) = K,
// [640,768) = V (transposed out).
__global__ __launch_bounds__(256) void gemm_qkv(
    const __hip_bfloat16* __restrict__ qb, const __hip_bfloat16* __restrict__ kb,
    const __hip_bfloat16* __restrict__ vb, const __hip_bfloat16* __restrict__ Wqb,
    const __hip_bfloat16* __restrict__ Wkb, const __hip_bfloat16* __restrict__ Wvb,
    __hip_bfloat16* __restrict__ QO, __hip_bfloat16* __restrict__ Kws,
    __hip_bfloat16* __restrict__ VT)
{
    __shared__ __hip_bfloat16 sA[3 * 4096];
    __shared__ __hip_bfloat16 sW[3 * 8192];
    int id = blockIdx.x;
    const __hip_bfloat16 *A, *W;
    void* C;
    int N, mode, bx, by;
    if (id < 512)      { A = qb; W = Wqb; C = QO;  N = 1024; mode = 0; bx = id & 7; by = id >> 3; }
    else if (id < 640) { id -= 512; A = kb; W = Wkb; C = Kws; N = 256; mode = 0; bx = id & 1; by = id >> 1; }
    else               { id -= 640; A = vb; W = Wvb; C = VT;  N = 256; mode = 1; bx = id & 1; by = id >> 1; }
    gemm_core(A, W, C, N, mode, by * 64, bx * 128, sA, sW);
}

__global__ __launch_bounds__(256) void gemm_out(
    const __hip_bfloat16* __restrict__ QO, const __hip_bfloat16* __restrict__ Wob,
    float* __restrict__ out)
{
    __shared__ __hip_bfloat16 sA[3 * 4096];
    __shared__ __hip_bfloat16 sW[3 * 8192];
    const int id = blockIdx.x;   // 512 blocks: 64 x 8 tiles
    gemm_core(QO, Wob, out, 1024, 2, (id >> 3) * 64, (id & 7) * 128, sA, sW);
}

// ---------------------------------------------------------------------------
// Causal GQA flash attention — UNCHANGED from r4 (63.7 µs verified):
// r2 pairing {bx, 31-bx}, stride-64 XOR-swizzled sK/sV, T13 defer-max,
// no setprio.
// ---------------------------------------------------------------------------
__global__ __launch_bounds__(256) void attn(
    __hip_bfloat16* QO,
    const __hip_bfloat16* __restrict__ Kp,
    const __hip_bfloat16* __restrict__ VT)
{
    __shared__ __hip_bfloat16 sK[64][64];
    __shared__ __hip_bfloat16 sV[64][64];

    const int bx   = blockIdx.x;    // 0..15
    const int h    = blockIdx.y;
    const int b    = blockIdx.z;
    const int hk   = h >> 2;        // repeat_interleave mapping
    const int tid  = threadIdx.x;
    const int l    = tid & 63;
    const int w    = tid >> 6;
    const int quad = l >> 4;
    const int lan  = l & 15;
    const bool hi  = quad >= 2;
    const float KSC = 0.125f * 1.44269504088896340736f;

    // ds_bpermute byte indices for the P^T redistribution (verified r2).
    const int idxA = (((quad & 1) * 32) + lan) * 4;  // w2 = 0,1
    const int idxB = idxA + 64;                      // w2 = 2,3

    // staging: row kr, logical 16B slots s0c,(s0c+1); stored XOR-swizzled.
    const int kr  = tid >> 2;
    const int s0c = (tid & 3) * 2;
    const int sw0 = (s0c ^ (kr & 7)) * 8;        // swizzled elem offset
    const int sw1 = ((s0c + 1) ^ (kr & 7)) * 8;
    const int kc  = s0c * 8;                     // linear global elem offset

    // swizzled read offsets (row&7 == lan&7 for all fragment rows)
    const int swq0 = (quad ^ (lan & 7)) * 8;
    const int swq1 = ((4 + quad) ^ (lan & 7)) * 8;

    const __hip_bfloat16* kg =
        Kp + ((size_t)((b * S_ + kr) * NKV_) + hk) * HD_ + kc;
    const __hip_bfloat16* vg =
        VT + ((size_t)((b * NKV_ + hk) * HD_) + kr) * S_ + kc;
    const size_t kstride = (size_t)64 * NKV_ * HD_;

    for (int half = 0; half < 2; ++half) {
        const int qt  = half ? (31 - bx) : bx;
        const int qr0 = qt * 64 + w * 16;
        const int qme = qr0 + lan;  // this lane's q-row

        const __hip_bfloat16* qp =
            QO + ((size_t)((b * S_ + qme) * NH_) + h) * HD_ + quad * 8;
        const bf16x8 aq0 = *reinterpret_cast<const bf16x8*>(qp);
        const bf16x8 aq1 = *reinterpret_cast<const bf16x8*>(qp + 32);

        float m_i = -3.0e38f, l_i = 0.f;
        f32x4 acc_o[4] = {};

        uint4 kv0 = *reinterpret_cast<const uint4*>(kg);
        uint4 kv1 = *reinterpret_cast<const uint4*>(kg + 8);
        uint4 vv0 = *reinterpret_cast<const uint4*>(vg);
        uint4 vv1 = *reinterpret_cast<const uint4*>(vg + 8);

        for (int kt = 0; kt <= qt; ++kt) {
            __syncthreads();  // staging overwrite vs prev iter's reads
            *reinterpret_cast<uint4*>(&sK[kr][sw0]) = kv0;
            *reinterpret_cast<uint4*>(&sK[kr][sw1]) = kv1;
            *reinterpret_cast<uint4*>(&sV[kr][sw0]) = vv0;
            *reinterpret_cast<uint4*>(&sV[kr][sw1]) = vv1;
            __syncthreads();

            if (kt < qt) {  // prefetch next K/V tile
                const __hip_bfloat16* kn = kg + (size_t)(kt + 1) * kstride;
                const __hip_bfloat16* vn = vg + (size_t)(kt + 1) * 64;
                kv0 = *reinterpret_cast<const uint4*>(kn);
                kv1 = *reinterpret_cast<const uint4*>(kn + 8);
                vv0 = *reinterpret_cast<const uint4*>(vn);
                vv1 = *reinterpret_cast<const uint4*>(vn + 8);
            }

            // S^T = K Q^T : accs[j][r] = S[q=qme][k = kt*64 + j*16 + quad*4 + r]
            f32x4 accs[4] = {};
#pragma unroll
            for (int j = 0; j < 4; ++j) {
                bf16x8 bk0 = *reinterpret_cast<const bf16x8*>(&sK[j * 16 + lan][swq0]);
                accs[j] = MFMA16(bk0, aq0, accs[j]);
                bf16x8 bk1 = *reinterpret_cast<const bf16x8*>(&sK[j * 16 + lan][swq1]);
                accs[j] = MFMA16(bk1, aq1, accs[j]);
            }

            if (kt == qt) {  // causal mask on the diagonal tile
#pragma unroll
                for (int j = 0; j < 4; ++j)
#pragma unroll
                    for (int r = 0; r < 4; ++r) {
                        const int kcg = kt * 64 + j * 16 + quad * 4 + r;
                        if (kcg > qme) accs[j][r] = -1e30f;
                    }
            }

            // ---- per-lane online softmax (one q-row per lane) ----
            float tm = accs[0][0];
#pragma unroll
            for (int j = 0; j < 4; ++j)
#pragma unroll
                for (int r = 0; r < 4; ++r) tm = fmaxf(tm, accs[j][r]);
            tm = fmaxf(tm, __shfl_xor(tm, 16));
            tm = fmaxf(tm, __shfl_xor(tm, 32));

            // T13 defer-max: rescale only if the row max grew past 2^8.
            if (__any((tm - m_i) * KSC > 8.0f)) {
                const float mnew  = fmaxf(m_i, tm);
                const float alpha = exp2f((m_i - mnew) * KSC);
                l_i *= alpha;
                m_i  = mnew;
#pragma unroll
                for (int dd = 0; dd < 4; ++dd)
#pragma unroll
                    for (int r = 0; r < 4; ++r) acc_o[dd][r] *= alpha;
            }

            float ps = 0.f;
#pragma unroll
            for (int j = 0; j < 4; ++j)
#pragma unroll
                for (int r = 0; r < 4; ++r) {
                    const float p = exp2f((accs[j][r] - m_i) * KSC);
                    accs[j][r] = p;
                    ps += p;
                }
            ps += __shfl_xor(ps, 16);
            ps += __shfl_xor(ps, 32);
            l_i += ps;

            // ---- pack P to bf16 pairs ----
            uint pk[4][2];
#pragma unroll
            for (int j = 0; j < 4; ++j)
#pragma unroll
                for (int hh = 0; hh < 2; ++hh) {
                    union { __hip_bfloat16 bh[2]; uint u; } t;
                    t.bh[0] = __float2bfloat16(accs[j][2 * hh]);
                    t.bh[1] = __float2bfloat16(accs[j][2 * hh + 1]);
                    pk[j][hh] = t.u;
                }

            // ---- O^T += V^T P^T ----
#pragma unroll
            for (int kk = 0; kk < 2; ++kk) {
                union { uint u[4]; bf16x8 v; } pb;
#pragma unroll
                for (int w2 = 0; w2 < 4; ++w2) {
                    const int idx = (w2 & 2) ? idxB : idxA;
                    const uint a = (uint)__builtin_amdgcn_ds_bpermute(
                        idx, (int)pk[2 * kk][w2 & 1]);
                    const uint bb = (uint)__builtin_amdgcn_ds_bpermute(
                        idx, (int)pk[2 * kk + 1][w2 & 1]);
                    pb.u[w2] = hi ? bb : a;
                }
#pragma unroll
                for (int dd = 0; dd < 4; ++dd) {
                    const int swv = ((kk * 4 + quad) ^ (lan & 7)) * 8;
                    bf16x8 av = *reinterpret_cast<const bf16x8*>(
                        &sV[dd * 16 + lan][swv]);
                    acc_o[dd] = MFMA16(av, pb.v, acc_o[dd]);
                }
            }
        }

        // ---- epilogue: O^T[d][q] -> QO[b, q, h, d], packed 8B stores ----
        const float inv = 1.0f / l_i;
        __hip_bfloat16* op =
            QO + ((size_t)((b * S_ + qme) * NH_) + h) * HD_ + quad * 4;
#pragma unroll
        for (int dd = 0; dd < 4; ++dd) {
            union { __hip_bfloat16 bh[4]; uint2 u; } t;
#pragma unroll
            for (int r = 0; r < 4; ++r)
                t.bh[r] = __float2bfloat16(acc_o[dd][r] * inv);
            *reinterpret_cast<uint2*>(op + dd * 16) = t.u;
        }
    }
}

// ---------------------------------------------------------------------------
extern "C" void kernel_launch(void* const* d_in, const int* in_sizes, int n_in,
                              void* d_out, int out_size, void* d_ws, size_t ws_size,
                              hipStream_t stream) {
    // Contract (measured r1-r12): insertion order, all inputs f32,
    // mask(slot3)==tril, OUTPUT IS FLOAT32.
    const float* q  = (const float*)d_in[0];
    const float* k  = (const float*)d_in[1];
    const float* v  = (const float*)d_in[2];
    const float* Wq = (const float*)d_in[4];
    const float* Wk = (const float*)d_in[5];
    const float* Wv = (const float*)d_in[6];
    const float* Wo = (const float*)d_in[7];

    // workspace layout (bf16 elements), ~41 MB total
    __hip_bfloat16* ws = (__hip_bfloat16*)d_ws;
    __hip_bfloat16* qb   = ws;                    // 4M
    __hip_bfloat16* kb   = qb  + 4194304;         // 4M
    __hip_bfloat16* vb   = kb  + 4194304;         // 4M
    __hip_bfloat16* QO   = vb  + 4194304;         // 4M  [B,S,NH,HD]
    __hip_bfloat16* Kws  = QO  + 4194304;         // 1M  [B,S,NKV,HD]
    __hip_bfloat16* VT   = Kws + 1048576;         // 1M  [B,NKV,HD,S]
    __hip_bfloat16* Wqb  = VT  + 1048576;         // 1M
    __hip_bfloat16* Wob  = Wqb + 1048576;         // 1M
    __hip_bfloat16* Wkb  = Wob + 1048576;         // 256K
    __hip_bfloat16* Wvb  = Wkb + 262144;          // 256K

    cvt_all<<<dim3(7424), 256, 0, stream>>>(
        q, k, v, Wq, Wo, Wk, Wv, qb, kb, vb, Wqb, Wob, Wkb, Wvb);

    gemm_qkv<<<dim3(768), 256, 0, stream>>>(
        qb, kb, vb, Wqb, Wkb, Wvb, QO, Kws, VT);

    attn<<<dim3(16, NH_, B_), 256, 0, stream>>>(QO, Kws, VT);

    gemm_out<<<dim3(512), 256, 0, stream>>>(QO, Wob, (float*)d_out);
}

// Round 6
// 213.841 us; speedup vs baseline: 1.0239x; 1.0239x over previous
//
#include <hip/hip_runtime.h>
#include <hip/hip_bf16.h>

typedef __attribute__((ext_vector_type(8))) short bf16x8;
typedef __attribute__((ext_vector_type(4))) float f32x4;

#define MFMA16(a, b, c) __builtin_amdgcn_mfma_f32_16x16x32_bf16((a), (b), (c), 0, 0, 0)
#define ASYNC16(g, l)                                                     \
    __builtin_amdgcn_global_load_lds(                                     \
        (const __attribute__((address_space(1))) void*)(g),               \
        (__attribute__((address_space(3))) void*)(l), 16, 0, 0)

constexpr int B_ = 2, S_ = 2048, E_ = 1024, NH_ = 16, NKV_ = 4, HD_ = 64;

// ---------------------------------------------------------------------------
// fp32 -> bf16 conversion, flat 1D grid. (r4-verified)
// ---------------------------------------------------------------------------
__global__ __launch_bounds__(256) void cvt_all(
    const float* __restrict__ s0, const float* __restrict__ s1,
    const float* __restrict__ s2, const float* __restrict__ s3,
    const float* __restrict__ s4, const float* __restrict__ s5,
    const float* __restrict__ s6,
    __hip_bfloat16* __restrict__ d0, __hip_bfloat16* __restrict__ d1,
    __hip_bfloat16* __restrict__ d2, __hip_bfloat16* __restrict__ d3,
    __hip_bfloat16* __restrict__ d4, __hip_bfloat16* __restrict__ d5,
    __hip_bfloat16* __restrict__ d6)
{
    int id = blockIdx.x;
    const float* s;
    __hip_bfloat16* d;
    if (id < 6144) {
        const int which = id >> 11;
        s = which == 0 ? s0 : (which == 1 ? s1 : s2);
        d = which == 0 ? d0 : (which == 1 ? d1 : d2);
        id &= 2047;
    } else if (id < 6656) { s = s3; d = d3; id -= 6144; }
    else if (id < 7168)   { s = s4; d = d4; id -= 6656; }
    else if (id < 7296)   { s = s5; d = d5; id -= 7168; }
    else                  { s = s6; d = d6; id -= 7296; }

    const size_t i = ((size_t)id * 256 + threadIdx.x) * 8;
    const float4 f0 = *reinterpret_cast<const float4*>(s + i);
    const float4 f1 = *reinterpret_cast<const float4*>(s + i + 4);
    union { __hip_bfloat16 h[8]; uint4 u; } t;
    t.h[0] = __float2bfloat16(f0.x); t.h[1] = __float2bfloat16(f0.y);
    t.h[2] = __float2bfloat16(f0.z); t.h[3] = __float2bfloat16(f0.w);
    t.h[4] = __float2bfloat16(f1.x); t.h[5] = __float2bfloat16(f1.y);
    t.h[6] = __float2bfloat16(f1.z); t.h[7] = __float2bfloat16(f1.w);
    *reinterpret_cast<uint4*>(d + i) = t.u;
}

// ---------------------------------------------------------------------------
// bf16 B^T GEMM core — REVERTED to the r4 structure (210.7 µs verified):
// 64x128 tile, BK=64, gload_lds 16B, 2-buffer prefetch with __syncthreads
// drain. The r5 counted-vmcnt 3-buffer graft regressed (+8 µs): T4 pays
// only inside a full 8-phase interleave (m218 / m232 regime gate).
// ---------------------------------------------------------------------------
__device__ __forceinline__ void gemm_core(
    const __hip_bfloat16* __restrict__ A,
    const __hip_bfloat16* __restrict__ W,
    void* __restrict__ C,
    const int N, const int mode, const int m0, const int n0,
    __hip_bfloat16* sA, __hip_bfloat16* sW)
{
    const int tid  = threadIdx.x;
    const int l    = tid & 63;
    const int w    = tid >> 6;
    const int quad = l >> 4;
    const int lan  = l & 15;
    const int wm   = (w >> 1) * 32;
    const int wn   = (w & 1) * 64;

    const int srow  = w * 8 + (l >> 3);
    const int scolL = (l & 7) * 8;                // linear LDS col (elems)
    const int scolG = ((l & 7) ^ (l >> 3)) * 8;   // inverse-swz global col

    f32x4 acc[2][4] = {};

#define STAGE(buf, kb)                                                    \
    {                                                                     \
        _Pragma("unroll")                                                 \
        for (int q = 0; q < 2; ++q) {                                     \
            const int r_ = q * 32 + srow;                                 \
            ASYNC16(A + (size_t)(m0 + r_) * E_ + (kb) + scolG,            \
                    sA + (buf) * 4096 + r_ * 64 + scolL);                 \
        }                                                                 \
        _Pragma("unroll")                                                 \
        for (int q = 0; q < 4; ++q) {                                     \
            const int r_ = q * 32 + srow;                                 \
            ASYNC16(W + (size_t)(n0 + r_) * E_ + (kb) + scolG,            \
                    sW + (buf) * 8192 + r_ * 64 + scolL);                 \
        }                                                                 \
    }

    STAGE(0, 0)
    int cur = 0;
#pragma unroll 1
    for (int t = 0; t < 16; ++t) {
        __syncthreads();  // implicit vmcnt(0): buf[cur] ready, buf[cur^1] free
        if (t < 15) STAGE(cur ^ 1, (t + 1) * 64)

#pragma unroll
        for (int kk = 0; kk < 2; ++kk) {
            bf16x8 af[2], bf[4];
            const int ca = ((kk * 4 + quad) ^ (lan & 7)) * 8;
#pragma unroll
            for (int i = 0; i < 2; ++i)
                af[i] = *reinterpret_cast<const bf16x8*>(
                    sA + cur * 4096 + (wm + i * 16 + lan) * 64 + ca);
#pragma unroll
            for (int j = 0; j < 4; ++j)
                bf[j] = *reinterpret_cast<const bf16x8*>(
                    sW + cur * 8192 + (wn + j * 16 + lan) * 64 + ca);
#pragma unroll
            for (int i = 0; i < 2; ++i)
#pragma unroll
                for (int j = 0; j < 4; ++j)
                    acc[i][j] = MFMA16(af[i], bf[j], acc[i][j]);
        }
        cur ^= 1;
    }
#undef STAGE

#pragma unroll
    for (int i = 0; i < 2; ++i)
#pragma unroll
        for (int j = 0; j < 4; ++j)
#pragma unroll
            for (int r = 0; r < 4; ++r) {
                const int gm = m0 + wm + i * 16 + quad * 4 + r;
                const int gn = n0 + wn + j * 16 + lan;
                const float v = acc[i][j][r];
                if (mode == 2) {
                    ((float*)C)[(size_t)gm * N + gn] = v;
                } else {
                    const __hip_bfloat16 hv = __float2bfloat16(v);
                    if (mode == 0)
                        ((__hip_bfloat16*)C)[(size_t)gm * N + gn] = hv;
                    else  // V-transpose: [B,NKV,HD,S]
                        ((__hip_bfloat16*)C)
                            [((size_t)(gm >> 11) * N + gn) * (size_t)S_ +
                             (gm & 2047)] = hv;
                }
            }
}

// Fused Q/K/V projections, 64x128 tiles: blocks [0,512) = Q, [512,640) = K,
// [640,768) = V (transposed out).
__global__ __launch_bounds__(256) void gemm_qkv(
    const __hip_bfloat16* __restrict__ qb, const __hip_bfloat16* __restrict__ kb,
    const __hip_bfloat16* __restrict__ vb, const __hip_bfloat16* __restrict__ Wqb,
    const __hip_bfloat16* __restrict__ Wkb, const __hip_bfloat16* __restrict__ Wvb,
    __hip_bfloat16* __restrict__ QO, __hip_bfloat16* __restrict__ Kws,
    __hip_bfloat16* __restrict__ VT)
{
    __shared__ __hip_bfloat16 sA[2 * 4096];
    __shared__ __hip_bfloat16 sW[2 * 8192];
    int id = blockIdx.x;
    const __hip_bfloat16 *A, *W;
    void* C;
    int N, mode, bx, by;
    if (id < 512)      { A = qb; W = Wqb; C = QO;  N = 1024; mode = 0; bx = id & 7; by = id >> 3; }
    else if (id < 640) { id -= 512; A = kb; W = Wkb; C = Kws; N = 256; mode = 0; bx = id & 1; by = id >> 1; }
    else               { id -= 640; A = vb; W = Wvb; C = VT;  N = 256; mode = 1; bx = id & 1; by = id >> 1; }
    gemm_core(A, W, C, N, mode, by * 64, bx * 128, sA, sW);
}

__global__ __launch_bounds__(256) void gemm_out(
    const __hip_bfloat16* __restrict__ QO, const __hip_bfloat16* __restrict__ Wob,
    float* __restrict__ out)
{
    __shared__ __hip_bfloat16 sA[2 * 4096];
    __shared__ __hip_bfloat16 sW[2 * 8192];
    const int id = blockIdx.x;   // 512 blocks: 64 x 8 tiles
    gemm_core(QO, Wob, out, 1024, 2, (id >> 3) * 64, (id & 7) * 128, sA, sW);
}

// ---------------------------------------------------------------------------
// Causal GQA flash attention r6: r4 (63.7 µs verified) + DOUBLE-BUFFERED
// K/V LDS -> ONE barrier per K-tile (was 2; 66 convoy points -> 35/block).
// Race audit: wave stores to buf[cur] at iter kt only after passing barrier
// kt-1, which it reached only after all waves finished computing from
// buf[cur] at iter kt-2 (program order) -> WAR-safe with a single barrier.
// The first store of each half is guarded by one extra __syncthreads().
// Everything else (pairing {bx,31-bx}, swizzle, defer-max, no setprio)
// identical to r4.
// ---------------------------------------------------------------------------
__global__ __launch_bounds__(256) void attn(
    __hip_bfloat16* QO,
    const __hip_bfloat16* __restrict__ Kp,
    const __hip_bfloat16* __restrict__ VT)
{
    __shared__ __hip_bfloat16 sK[2][64][64];
    __shared__ __hip_bfloat16 sV[2][64][64];

    const int bx   = blockIdx.x;    // 0..15
    const int h    = blockIdx.y;
    const int b    = blockIdx.z;
    const int hk   = h >> 2;        // repeat_interleave mapping
    const int tid  = threadIdx.x;
    const int l    = tid & 63;
    const int w    = tid >> 6;
    const int quad = l >> 4;
    const int lan  = l & 15;
    const bool hi  = quad >= 2;
    const float KSC = 0.125f * 1.44269504088896340736f;

    // ds_bpermute byte indices for the P^T redistribution (verified r2).
    const int idxA = (((quad & 1) * 32) + lan) * 4;  // w2 = 0,1
    const int idxB = idxA + 64;                      // w2 = 2,3

    // staging: row kr, logical 16B slots s0c,(s0c+1); stored XOR-swizzled.
    const int kr  = tid >> 2;
    const int s0c = (tid & 3) * 2;
    const int sw0 = (s0c ^ (kr & 7)) * 8;        // swizzled elem offset
    const int sw1 = ((s0c + 1) ^ (kr & 7)) * 8;
    const int kc  = s0c * 8;                     // linear global elem offset

    // swizzled read offsets (row&7 == lan&7 for all fragment rows)
    const int swq0 = (quad ^ (lan & 7)) * 8;
    const int swq1 = ((4 + quad) ^ (lan & 7)) * 8;

    const __hip_bfloat16* kg =
        Kp + ((size_t)((b * S_ + kr) * NKV_) + hk) * HD_ + kc;
    const __hip_bfloat16* vg =
        VT + ((size_t)((b * NKV_ + hk) * HD_) + kr) * S_ + kc;
    const size_t kstride = (size_t)64 * NKV_ * HD_;

    for (int half = 0; half < 2; ++half) {
        const int qt  = half ? (31 - bx) : bx;
        const int qr0 = qt * 64 + w * 16;
        const int qme = qr0 + lan;  // this lane's q-row

        const __hip_bfloat16* qp =
            QO + ((size_t)((b * S_ + qme) * NH_) + h) * HD_ + quad * 8;
        const bf16x8 aq0 = *reinterpret_cast<const bf16x8*>(qp);
        const bf16x8 aq1 = *reinterpret_cast<const bf16x8*>(qp + 32);

        float m_i = -3.0e38f, l_i = 0.f;
        f32x4 acc_o[4] = {};

        uint4 kv0 = *reinterpret_cast<const uint4*>(kg);
        uint4 kv1 = *reinterpret_cast<const uint4*>(kg + 8);
        uint4 vv0 = *reinterpret_cast<const uint4*>(vg);
        uint4 vv1 = *reinterpret_cast<const uint4*>(vg + 8);

        int cur = 0;
        __syncthreads();  // guard prev half's last reads of buf[0]

        for (int kt = 0; kt <= qt; ++kt) {
            // store prefetched tile into buf[cur] (WAR-safe: see header)
            *reinterpret_cast<uint4*>(&sK[cur][kr][sw0]) = kv0;
            *reinterpret_cast<uint4*>(&sK[cur][kr][sw1]) = kv1;
            *reinterpret_cast<uint4*>(&sV[cur][kr][sw0]) = vv0;
            *reinterpret_cast<uint4*>(&sV[cur][kr][sw1]) = vv1;
            __syncthreads();  // single barrier: writes visible to all waves

            if (kt < qt) {  // prefetch next K/V tile (lands during compute)
                const __hip_bfloat16* kn = kg + (size_t)(kt + 1) * kstride;
                const __hip_bfloat16* vn = vg + (size_t)(kt + 1) * 64;
                kv0 = *reinterpret_cast<const uint4*>(kn);
                kv1 = *reinterpret_cast<const uint4*>(kn + 8);
                vv0 = *reinterpret_cast<const uint4*>(vn);
                vv1 = *reinterpret_cast<const uint4*>(vn + 8);
            }

            // S^T = K Q^T : accs[j][r] = S[q=qme][k = kt*64 + j*16 + quad*4 + r]
            f32x4 accs[4] = {};
#pragma unroll
            for (int j = 0; j < 4; ++j) {
                bf16x8 bk0 = *reinterpret_cast<const bf16x8*>(&sK[cur][j * 16 + lan][swq0]);
                accs[j] = MFMA16(bk0, aq0, accs[j]);
                bf16x8 bk1 = *reinterpret_cast<const bf16x8*>(&sK[cur][j * 16 + lan][swq1]);
                accs[j] = MFMA16(bk1, aq1, accs[j]);
            }

            if (kt == qt) {  // causal mask on the diagonal tile
#pragma unroll
                for (int j = 0; j < 4; ++j)
#pragma unroll
                    for (int r = 0; r < 4; ++r) {
                        const int kcg = kt * 64 + j * 16 + quad * 4 + r;
                        if (kcg > qme) accs[j][r] = -1e30f;
                    }
            }

            // ---- per-lane online softmax (one q-row per lane) ----
            float tm = accs[0][0];
#pragma unroll
            for (int j = 0; j < 4; ++j)
#pragma unroll
                for (int r = 0; r < 4; ++r) tm = fmaxf(tm, accs[j][r]);
            tm = fmaxf(tm, __shfl_xor(tm, 16));
            tm = fmaxf(tm, __shfl_xor(tm, 32));

            // T13 defer-max: rescale only if the row max grew past 2^8.
            if (__any((tm - m_i) * KSC > 8.0f)) {
                const float mnew  = fmaxf(m_i, tm);
                const float alpha = exp2f((m_i - mnew) * KSC);
                l_i *= alpha;
                m_i  = mnew;
#pragma unroll
                for (int dd = 0; dd < 4; ++dd)
#pragma unroll
                    for (int r = 0; r < 4; ++r) acc_o[dd][r] *= alpha;
            }

            float ps = 0.f;
#pragma unroll
            for (int j = 0; j < 4; ++j)
#pragma unroll
                for (int r = 0; r < 4; ++r) {
                    const float p = exp2f((accs[j][r] - m_i) * KSC);
                    accs[j][r] = p;
                    ps += p;
                }
            ps += __shfl_xor(ps, 16);
            ps += __shfl_xor(ps, 32);
            l_i += ps;

            // ---- pack P to bf16 pairs ----
            uint pk[4][2];
#pragma unroll
            for (int j = 0; j < 4; ++j)
#pragma unroll
                for (int hh = 0; hh < 2; ++hh) {
                    union { __hip_bfloat16 bh[2]; uint u; } t;
                    t.bh[0] = __float2bfloat16(accs[j][2 * hh]);
                    t.bh[1] = __float2bfloat16(accs[j][2 * hh + 1]);
                    pk[j][hh] = t.u;
                }

            // ---- O^T += V^T P^T ----
#pragma unroll
            for (int kk = 0; kk < 2; ++kk) {
                union { uint u[4]; bf16x8 v; } pb;
#pragma unroll
                for (int w2 = 0; w2 < 4; ++w2) {
                    const int idx = (w2 & 2) ? idxB : idxA;
                    const uint a = (uint)__builtin_amdgcn_ds_bpermute(
                        idx, (int)pk[2 * kk][w2 & 1]);
                    const uint bb = (uint)__builtin_amdgcn_ds_bpermute(
                        idx, (int)pk[2 * kk + 1][w2 & 1]);
                    pb.u[w2] = hi ? bb : a;
                }
#pragma unroll
                for (int dd = 0; dd < 4; ++dd) {
                    const int swv = ((kk * 4 + quad) ^ (lan & 7)) * 8;
                    bf16x8 av = *reinterpret_cast<const bf16x8*>(
                        &sV[cur][dd * 16 + lan][swv]);
                    acc_o[dd] = MFMA16(av, pb.v, acc_o[dd]);
                }
            }
            cur ^= 1;
        }

        // ---- epilogue: O^T[d][q] -> QO[b, q, h, d], packed 8B stores ----
        const float inv = 1.0f / l_i;
        __hip_bfloat16* op =
            QO + ((size_t)((b * S_ + qme) * NH_) + h) * HD_ + quad * 4;
#pragma unroll
        for (int dd = 0; dd < 4; ++dd) {
            union { __hip_bfloat16 bh[4]; uint2 u; } t;
#pragma unroll
            for (int r = 0; r < 4; ++r)
                t.bh[r] = __float2bfloat16(acc_o[dd][r] * inv);
            *reinterpret_cast<uint2*>(op + dd * 16) = t.u;
        }
    }
}

// ---------------------------------------------------------------------------
extern "C" void kernel_launch(void* const* d_in, const int* in_sizes, int n_in,
                              void* d_out, int out_size, void* d_ws, size_t ws_size,
                              hipStream_t stream) {
    // Contract (measured r1-r12): insertion order, all inputs f32,
    // mask(slot3)==tril, OUTPUT IS FLOAT32.
    const float* q  = (const float*)d_in[0];
    const float* k  = (const float*)d_in[1];
    const float* v  = (const float*)d_in[2];
    const float* Wq = (const float*)d_in[4];
    const float* Wk = (const float*)d_in[5];
    const float* Wv = (const float*)d_in[6];
    const float* Wo = (const float*)d_in[7];

    // workspace layout (bf16 elements), ~41 MB total
    __hip_bfloat16* ws = (__hip_bfloat16*)d_ws;
    __hip_bfloat16* qb   = ws;                    // 4M
    __hip_bfloat16* kb   = qb  + 4194304;         // 4M
    __hip_bfloat16* vb   = kb  + 4194304;         // 4M
    __hip_bfloat16* QO   = vb  + 4194304;         // 4M  [B,S,NH,HD]
    __hip_bfloat16* Kws  = QO  + 4194304;         // 1M  [B,S,NKV,HD]
    __hip_bfloat16* VT   = Kws + 1048576;         // 1M  [B,NKV,HD,S]
    __hip_bfloat16* Wqb  = VT  + 1048576;         // 1M
    __hip_bfloat16* Wob  = Wqb + 1048576;         // 1M
    __hip_bfloat16* Wkb  = Wob + 1048576;         // 256K
    __hip_bfloat16* Wvb  = Wkb + 262144;          // 256K

    cvt_all<<<dim3(7424), 256, 0, stream>>>(
        q, k, v, Wq, Wo, Wk, Wv, qb, kb, vb, Wqb, Wob, Wkb, Wvb);

    gemm_qkv<<<dim3(768), 256, 0, stream>>>(
        qb, kb, vb, Wqb, Wkb, Wvb, QO, Kws, VT);

    attn<<<dim3(16, NH_, B_), 256, 0, stream>>>(QO, Kws, VT);

    gemm_out<<<dim3(512), 256, 0, stream>>>(QO, Wob, (float*)d_out);
}